// Round 7
// baseline (506.516 us; speedup 1.0000x reference)
//
#include <hip/hip_runtime.h>

#define H 64
#define NN 100000
#define NE 1000000
#define EPS 1e-6f

// ROUND 13: overlap, not pipes. r12 confirmed the atomic-sector model
// (WRITE 2.25e6 -> 0.50e6 KB, 1865 -> 417us); no pipe is saturated now
// (VALU 53%, HBM 34%, atomics ~230us overlappable) but occupancy is 31%
// (41KB LDS -> 3 blocks/CU): barrier-lockstep + end-of-block atomic bursts
// can't hide under each other. Changes:
//  1) W staged in 12KB QUARTERS (was 24KB halves): LDS 41 -> 29.7KB ->
//     5 blocks/CU = 20 waves = 62% occupancy. Same total staging traffic.
//  2) nontemporal loads on the once-streamed edges reads (GEMM phases 0-3
//     + residual re-read): stops the 256MB stream from evicting the hot
//     25.6MB nodes gather table (FETCH was 618MB vs ~314 ideal).
// GEMM tile, atomic row-transpose epilogue, LN: unchanged from r12.

typedef __attribute__((ext_vector_type(4))) float f32v4;

static __device__ __forceinline__ f32v4 ntload4(const float* p) {
  return __builtin_nontemporal_load((const f32v4*)p);
}

__global__ __launch_bounds__(256, 4) void edge_q(
    const float* __restrict__ nodes, const float* __restrict__ edges,
    const int* __restrict__ senders, const int* __restrict__ receivers,
    const float* __restrict__ We, const float* __restrict__ be,
    const float* __restrict__ ln_s, const float* __restrict__ ln_b,
    float* recv_agg, float* __restrict__ edges_out) {
  __shared__ __align__(16) float Wb[48 * 64];   // 12 KB: current W quarter
  __shared__ __align__(16) float aT[16 * 256];  // 16 KB: [k][edge] per phase;
                                                // reused as 4x4KB wave slices
  __shared__ int rBlk[256];                     // 1 KB
  const int tid = threadIdx.x;
  const int e0 = blockIdx.x * 256;
  const int myE = e0 + tid;
  const int eC = myE < NE ? myE : NE - 1;  // clamped: loads only
  const int sIdx = senders[eC];
  const int rIdx = receivers[eC];
  rBlk[tid] = rIdx;

  float acc[8][8];
#pragma unroll
  for (int j = 0; j < 8; ++j)
#pragma unroll
    for (int i = 0; i < 8; ++i) acc[j][i] = 0.0f;

  const int te = (tid >> 3) * 8;  // 32 groups x 8 edges
  const int tc = (tid & 7) * 8;   // 8 groups x 8 cols

  // A chunk for phase p: p<4 edges (nt: once-streamed), p<8 sender,
  // else receiver. One 64B line of this thread's own row.
#define LOAD_A(P)                                                              \
  {                                                                            \
    const int p_ = (P);                                                        \
    if (p_ < 4) {                                                              \
      const float* s_ = edges + (size_t)eC * H + p_ * 16;                      \
      v0 = ntload4(s_ + 0);  v1 = ntload4(s_ + 4);                             \
      v2 = ntload4(s_ + 8);  v3 = ntload4(s_ + 12);                            \
    } else {                                                                   \
      const float* s_ = (p_ < 8) ? nodes + (size_t)sIdx * H + (p_ - 4) * 16    \
                                 : nodes + (size_t)rIdx * H + (p_ - 8) * 16;   \
      v0 = *(const f32v4*)(s_ + 0);  v1 = *(const f32v4*)(s_ + 4);             \
      v2 = *(const f32v4*)(s_ + 8);  v3 = *(const f32v4*)(s_ + 12);            \
    }                                                                          \
  }

  // transpose write: aT[k][e=tid]; bank = tid%32: conflict-free
#define WRITE_AT()                                                             \
  {                                                                            \
    aT[0 * 256 + tid] = v0.x;  aT[1 * 256 + tid] = v0.y;                       \
    aT[2 * 256 + tid] = v0.z;  aT[3 * 256 + tid] = v0.w;                       \
    aT[4 * 256 + tid] = v1.x;  aT[5 * 256 + tid] = v1.y;                       \
    aT[6 * 256 + tid] = v1.z;  aT[7 * 256 + tid] = v1.w;                       \
    aT[8 * 256 + tid] = v2.x;  aT[9 * 256 + tid] = v2.y;                       \
    aT[10 * 256 + tid] = v2.z; aT[11 * 256 + tid] = v2.w;                      \
    aT[12 * 256 + tid] = v3.x; aT[13 * 256 + tid] = v3.y;                      \
    aT[14 * 256 + tid] = v3.z; aT[15 * 256 + tid] = v3.w;                      \
  }

#define COMPUTE_PHASE(P3)                                                      \
  {                                                                            \
    const float* __restrict__ wp = Wb + (P3) * (16 * 64);                      \
    _Pragma("unroll 4")                                                        \
    for (int kk = 0; kk < 16; ++kk) {                                          \
      f32v4 a0 = *(const f32v4*)(&aT[kk * 256 + te + 0]);                      \
      f32v4 a1 = *(const f32v4*)(&aT[kk * 256 + te + 4]);                      \
      f32v4 w0 = *(const f32v4*)(&wp[kk * 64 + tc + 0]);                       \
      f32v4 w1 = *(const f32v4*)(&wp[kk * 64 + tc + 4]);                       \
      const float av[8] = {a0.x, a0.y, a0.z, a0.w, a1.x, a1.y, a1.z, a1.w};    \
      const float wv[8] = {w0.x, w0.y, w0.z, w0.w, w1.x, w1.y, w1.z, w1.w};    \
      _Pragma("unroll")                                                        \
      for (int j = 0; j < 8; ++j)                                              \
        _Pragma("unroll")                                                      \
        for (int i = 0; i < 8; ++i)                                            \
          acc[j][i] = fmaf(av[j], wv[i], acc[j][i]);                           \
    }                                                                          \
  }

  // 4 quarters x 3 phases of K=16. W quarter (48x64 = 12KB) staged at the
  // quarter head, piggybacking on phase 0's barrier pair. All global loads
  // issued BEFORE the barrier so they fly during the previous compute.
#pragma unroll 1
  for (int q = 0; q < 4; ++q) {
    const float* wsrc = We + (size_t)q * (48 * 64);
    f32v4 wq0 = *(const f32v4*)(wsrc + (0 * 256 + tid) * 4);
    f32v4 wq1 = *(const f32v4*)(wsrc + (1 * 256 + tid) * 4);
    f32v4 wq2 = *(const f32v4*)(wsrc + (2 * 256 + tid) * 4);
    f32v4 v0, v1, v2, v3;
    LOAD_A(q * 3);
    __syncthreads();  // prev quarter's compute done reading aT + Wb
    *(f32v4*)(&Wb[(0 * 256 + tid) * 4]) = wq0;
    *(f32v4*)(&Wb[(1 * 256 + tid) * 4]) = wq1;
    *(f32v4*)(&Wb[(2 * 256 + tid) * 4]) = wq2;
    WRITE_AT();
    __syncthreads();
    COMPUTE_PHASE(0);
#pragma unroll 1
    for (int p3 = 1; p3 < 3; ++p3) {
      LOAD_A(q * 3 + p3);
      __syncthreads();  // prev compute done reading aT
      WRITE_AT();
      __syncthreads();
      COMPUTE_PHASE(p3);
    }
  }
#undef LOAD_A
#undef WRITE_AT
#undef COMPUTE_PHASE
  __syncthreads();  // all waves done reading aT: safe to reuse as slices

  // ---- epilogue part 1: bias -> LN -> store; acc := n (pre-residual) ----
  const f32v4 be0 = *(const f32v4*)(be + tc);
  const f32v4 be1 = *(const f32v4*)(be + tc + 4);
  const f32v4 se0 = *(const f32v4*)(ln_s + tc);
  const f32v4 se1 = *(const f32v4*)(ln_s + tc + 4);
  const f32v4 bi0 = *(const f32v4*)(ln_b + tc);
  const f32v4 bi1 = *(const f32v4*)(ln_b + tc + 4);
  const float bb[8] = {be0.x, be0.y, be0.z, be0.w, be1.x, be1.y, be1.z, be1.w};
  const float ss[8] = {se0.x, se0.y, se0.z, se0.w, se1.x, se1.y, se1.z, se1.w};
  const float ll[8] = {bi0.x, bi0.y, bi0.z, bi0.w, bi1.x, bi1.y, bi1.z, bi1.w};

#pragma unroll
  for (int j = 0; j < 8; ++j) {
    const int row = te + j;
    const int ge = e0 + row;
    const bool valid = ge < NE;
    const int geC = valid ? ge : NE - 1;
    // residual re-read: nontemporal (once-streamed region; don't evict the
    // nodes gather table). Issued before shuffles/atomics.
    const f32v4 r0 = ntload4(edges + (size_t)geC * H + tc);
    const f32v4 r1 = ntload4(edges + (size_t)geC * H + tc + 4);
    const float rr[8] = {r0.x, r0.y, r0.z, r0.w, r1.x, r1.y, r1.z, r1.w};
    float t8[8];
#pragma unroll
    for (int i = 0; i < 8; ++i) {
      const float n = acc[j][i] + bb[i];
      acc[j][i] = n;  // keep pre-residual value for the atomic pass
      t8[i] = n + rr[i];
    }
    float s1 = 0.f, s2 = 0.f;
#pragma unroll
    for (int i = 0; i < 8; ++i) { s1 += t8[i]; s2 = fmaf(t8[i], t8[i], s2); }
    // row held by the 8 lanes sharing te: xor 1,2,4
    s1 += __shfl_xor(s1, 1, 64); s2 += __shfl_xor(s2, 1, 64);
    s1 += __shfl_xor(s1, 2, 64); s2 += __shfl_xor(s2, 2, 64);
    s1 += __shfl_xor(s1, 4, 64); s2 += __shfl_xor(s2, 4, 64);
    const float mean = s1 * (1.0f / 64.0f);
    const float var = s2 * (1.0f / 64.0f) - mean * mean;
    const float rstd = rsqrtf(var + EPS);
    if (valid) {
      f32v4 o0, o1;
      o0.x = (t8[0] - mean) * rstd * ss[0] + ll[0];
      o0.y = (t8[1] - mean) * rstd * ss[1] + ll[1];
      o0.z = (t8[2] - mean) * rstd * ss[2] + ll[2];
      o0.w = (t8[3] - mean) * rstd * ss[3] + ll[3];
      o1.x = (t8[4] - mean) * rstd * ss[4] + ll[4];
      o1.y = (t8[5] - mean) * rstd * ss[5] + ll[5];
      o1.z = (t8[6] - mean) * rstd * ss[6] + ll[6];
      o1.w = (t8[7] - mean) * rstd * ss[7] + ll[7];
      float* po = edges_out + (size_t)ge * H + tc;
      __builtin_nontemporal_store(o0, (f32v4*)(po + 0));
      __builtin_nontemporal_store(o1, (f32v4*)(po + 4));
    }
  }

  // ---- epilogue part 2: per-wave transpose -> row-contiguous atomics ----
  // Wave wv owns block rows [64wv,64wv+64) + a private 4KB slice of aT: no
  // cross-wave hazard, no barriers. One atomic instr per edge covers the
  // full 256B recv row (8 sectors, 1x amplification) -- the r12 win.
  const int wv = tid >> 6;
  const int l = tid & 63;
  float* slice = aT + wv * 1024;  // 16 rows x 64 cols
#pragma unroll 1
  for (int s = 0; s < 4; ++s) {
    if ((l >> 4) == s) {
      const int rb = ((l >> 3) & 1) * 8;  // slice-row base for this lane
#pragma unroll
      for (int j = 0; j < 8; ++j) {
        f32v4 x0, x1;
        x0.x = acc[j][0]; x0.y = acc[j][1]; x0.z = acc[j][2]; x0.w = acc[j][3];
        x1.x = acc[j][4]; x1.y = acc[j][5]; x1.z = acc[j][6]; x1.w = acc[j][7];
        *(f32v4*)(&slice[(rb + j) * 64 + tc + 0]) = x0;
        *(f32v4*)(&slice[(rb + j) * 64 + tc + 4]) = x1;
      }
    }
#pragma unroll 4
    for (int e = 0; e < 16; ++e) {
      const int row = wv * 64 + s * 16 + e;
      const int ge = e0 + row;
      if (ge < NE) {  // uniform per instruction
        const float v = slice[e * 64 + l];  // stride-1 across lanes: free
        atomicAdd(recv_agg + (size_t)rBlk[row] * H + l, v);
      }
    }
  }
}

// ---- node kernel: unchanged (not the bottleneck, ~36 µs).
__global__ __launch_bounds__(256, 3) void node_tiled(
    const float* __restrict__ nodes, const float* recv_agg,
    const float* __restrict__ Wn, const float* __restrict__ bn,
    const float* __restrict__ ln_s, const float* __restrict__ ln_b,
    float* nodes_out) {
  __shared__ __align__(16) float aT[64 * 64];    // 16 KB: [k-k0][n]
  __shared__ __align__(16) float Wb[128 * 64];   // 32 KB
  const int tid = threadIdx.x;
  const int n0 = blockIdx.x * 64;

#pragma unroll
  for (int t = 0; t < 8; ++t) {
    int ci = t * 256 + tid;
    *(float4*)(&Wb[ci * 4]) = *(const float4*)(Wn + ci * 4);
  }

  float acc[4][4];
#pragma unroll
  for (int j = 0; j < 4; ++j)
#pragma unroll
    for (int i = 0; i < 4; ++i) acc[j][i] = 0.0f;

  const int te = (tid >> 4) * 4;
  const int tc = (tid & 15) * 4;

#pragma unroll
  for (int p = 0; p < 2; ++p) {
    const int k0 = 64 * p;
#pragma unroll
    for (int t = 0; t < 4; ++t) {
      int ci = t * 256 + tid;                     // 1024 float4
      int n = ci & 63, kq = ci >> 6;              // kq 0..15
      int kg = k0 + kq * 4;
      int gn = n0 + n;
      int gnc = gn < NN ? gn : NN - 1;
      const float* src = (kg < 64) ? (nodes + (size_t)gnc * H + kg)
                                   : (recv_agg + (size_t)gnc * H + (kg - 64));
      float4 v = *(const float4*)src;
      aT[(kq * 4 + 0) * 64 + n] = v.x;
      aT[(kq * 4 + 1) * 64 + n] = v.y;
      aT[(kq * 4 + 2) * 64 + n] = v.z;
      aT[(kq * 4 + 3) * 64 + n] = v.w;
    }
    __syncthreads();
#pragma unroll 4
    for (int kk = 0; kk < 64; ++kk) {
      float4 a4 = *(const float4*)(&aT[kk * 64 + te]);
      float4 w4 = *(const float4*)(&Wb[(k0 + kk) * 64 + tc]);
      float av[4] = {a4.x, a4.y, a4.z, a4.w};
      float wv[4] = {w4.x, w4.y, w4.z, w4.w};
#pragma unroll
      for (int j = 0; j < 4; ++j)
#pragma unroll
        for (int i = 0; i < 4; ++i) acc[j][i] += av[j] * wv[i];
    }
    __syncthreads();
  }

  const float4 bev = *(const float4*)(bn + tc);
  const float4 sev = *(const float4*)(ln_s + tc);
  const float4 biv = *(const float4*)(ln_b + tc);
#pragma unroll
  for (int j = 0; j < 4; ++j) {
    int gn = n0 + te + j;
    bool valid = gn < NN;
    float4 nv;
    if (valid) nv = *(const float4*)(nodes + (size_t)gn * H + tc);
    else { nv.x = nv.y = nv.z = nv.w = 0.0f; }
    float t0 = acc[j][0] + bev.x + nv.x;
    float t1 = acc[j][1] + bev.y + nv.y;
    float t2 = acc[j][2] + bev.z + nv.z;
    float t3 = acc[j][3] + bev.w + nv.w;
    float s1 = t0 + t1 + t2 + t3;
    float s2 = t0 * t0 + t1 * t1 + t2 * t2 + t3 * t3;
    s1 += __shfl_xor(s1, 1, 64); s2 += __shfl_xor(s2, 1, 64);
    s1 += __shfl_xor(s1, 2, 64); s2 += __shfl_xor(s2, 2, 64);
    s1 += __shfl_xor(s1, 4, 64); s2 += __shfl_xor(s2, 4, 64);
    s1 += __shfl_xor(s1, 8, 64); s2 += __shfl_xor(s2, 8, 64);
    float mean = s1 * (1.0f / 64.0f);
    float var = s2 * (1.0f / 64.0f) - mean * mean;
    float rstd = rsqrtf(var + EPS);
    if (valid) {
      float4 o;
      o.x = (t0 - mean) * rstd * sev.x + biv.x;
      o.y = (t1 - mean) * rstd * sev.y + biv.y;
      o.z = (t2 - mean) * rstd * sev.z + biv.z;
      o.w = (t3 - mean) * rstd * sev.w + biv.w;
      *(float4*)(nodes_out + (size_t)gn * H + tc) = o;
    }
  }
}

extern "C" void kernel_launch(void* const* d_in, const int* in_sizes, int n_in,
                              void* d_out, int out_size, void* d_ws, size_t ws_size,
                              hipStream_t stream) {
  const float* nodes      = (const float*)d_in[0];
  const float* edges      = (const float*)d_in[1];
  const int*   senders    = (const int*)d_in[2];
  const int*   receivers  = (const int*)d_in[3];
  const float* We         = (const float*)d_in[4];
  const float* be         = (const float*)d_in[5];
  const float* Wn         = (const float*)d_in[6];
  const float* bn         = (const float*)d_in[7];
  const float* ln_n_scale = (const float*)d_in[8];
  const float* ln_n_bias  = (const float*)d_in[9];
  const float* ln_e_scale = (const float*)d_in[10];
  const float* ln_e_bias  = (const float*)d_in[11];

  float* out = (float*)d_out;
  float* nodes_out = out;                       // [NN,64]; doubles as recv_agg
  float* edges_out = out + (size_t)NN * H;      // [NE,64]

  (void)hipMemsetAsync(nodes_out, 0, (size_t)NN * H * sizeof(float), stream);
  edge_q<<<(NE + 255) / 256, 256, 0, stream>>>(
      nodes, edges, senders, receivers, We, be, ln_e_scale, ln_e_bias,
      nodes_out, edges_out);
  node_tiled<<<(NN + 63) / 64, 256, 0, stream>>>(nodes, nodes_out, Wn, bn,
                                                 ln_n_scale, ln_n_bias, nodes_out);
}

// Round 8
// 435.727 us; speedup vs baseline: 1.1625x; 1.1625x over previous
//
#include <hip/hip_runtime.h>

#define H 64
#define NN 100000
#define NE 1000000
#define EPS 1e-6f

// ROUND 14: r13 post-mortem showed BOTH r13 changes were wrong and the one
// structural win was right. (1) (256,4) re-capped VGPR at 128 -> spill
// (VGPR=64, +92MB writes, +171MB fetch) -- revert to (256,3) (r12 ran 84
// regs clean). (2) nontemporal LOADS on edges destroyed the L2/L3 hit of
// the epilogue residual re-read (+171MB HBM fetch) -- revert to cacheable
// loads; keep nt only on edges_out STORES (never re-read). KEEP: 12KB
// W-quarter staging (LDS 29.7KB -> 5 blocks/CU; occupancy rose 31->42%
// even while spilling). GEMM tile, row-contiguous atomic epilogue (the
// r12 sector win: 1x amplification), LN layout: unchanged from r12.

typedef __attribute__((ext_vector_type(4))) float f32v4;

__global__ __launch_bounds__(256, 3) void edge_q(
    const float* __restrict__ nodes, const float* __restrict__ edges,
    const int* __restrict__ senders, const int* __restrict__ receivers,
    const float* __restrict__ We, const float* __restrict__ be,
    const float* __restrict__ ln_s, const float* __restrict__ ln_b,
    float* recv_agg, float* __restrict__ edges_out) {
  __shared__ __align__(16) float Wb[48 * 64];   // 12 KB: current W quarter
  __shared__ __align__(16) float aT[16 * 256];  // 16 KB: [k][edge] per phase;
                                                // reused as 4x4KB wave slices
  __shared__ int rBlk[256];                     // 1 KB
  const int tid = threadIdx.x;
  const int e0 = blockIdx.x * 256;
  const int myE = e0 + tid;
  const int eC = myE < NE ? myE : NE - 1;  // clamped: loads only
  const int sIdx = senders[eC];
  const int rIdx = receivers[eC];
  rBlk[tid] = rIdx;

  float acc[8][8];
#pragma unroll
  for (int j = 0; j < 8; ++j)
#pragma unroll
    for (int i = 0; i < 8; ++i) acc[j][i] = 0.0f;

  const int te = (tid >> 3) * 8;  // 32 groups x 8 edges
  const int tc = (tid & 7) * 8;   // 8 groups x 8 cols

  // A chunk for phase p: p<4 edges, p<8 sender, else receiver.
  // One 64B line of this thread's own row; plain cacheable loads (the
  // residual re-read depends on these lines staying in L2/L3).
#define LOAD_A(P)                                                              \
  {                                                                            \
    const int p_ = (P);                                                        \
    const float* s_;                                                           \
    if (p_ < 4)      s_ = edges + (size_t)eC * H + p_ * 16;                    \
    else if (p_ < 8) s_ = nodes + (size_t)sIdx * H + (p_ - 4) * 16;            \
    else             s_ = nodes + (size_t)rIdx * H + (p_ - 8) * 16;            \
    v0 = *(const f32v4*)(s_ + 0);  v1 = *(const f32v4*)(s_ + 4);               \
    v2 = *(const f32v4*)(s_ + 8);  v3 = *(const f32v4*)(s_ + 12);              \
  }

  // transpose write: aT[k][e=tid]; bank = tid%32: conflict-free
#define WRITE_AT()                                                             \
  {                                                                            \
    aT[0 * 256 + tid] = v0.x;  aT[1 * 256 + tid] = v0.y;                       \
    aT[2 * 256 + tid] = v0.z;  aT[3 * 256 + tid] = v0.w;                       \
    aT[4 * 256 + tid] = v1.x;  aT[5 * 256 + tid] = v1.y;                       \
    aT[6 * 256 + tid] = v1.z;  aT[7 * 256 + tid] = v1.w;                       \
    aT[8 * 256 + tid] = v2.x;  aT[9 * 256 + tid] = v2.y;                       \
    aT[10 * 256 + tid] = v2.z; aT[11 * 256 + tid] = v2.w;                      \
    aT[12 * 256 + tid] = v3.x; aT[13 * 256 + tid] = v3.y;                      \
    aT[14 * 256 + tid] = v3.z; aT[15 * 256 + tid] = v3.w;                      \
  }

#define COMPUTE_PHASE(P3)                                                      \
  {                                                                            \
    const float* __restrict__ wp = Wb + (P3) * (16 * 64);                      \
    _Pragma("unroll 4")                                                        \
    for (int kk = 0; kk < 16; ++kk) {                                          \
      f32v4 a0 = *(const f32v4*)(&aT[kk * 256 + te + 0]);                      \
      f32v4 a1 = *(const f32v4*)(&aT[kk * 256 + te + 4]);                      \
      f32v4 w0 = *(const f32v4*)(&wp[kk * 64 + tc + 0]);                       \
      f32v4 w1 = *(const f32v4*)(&wp[kk * 64 + tc + 4]);                       \
      const float av[8] = {a0.x, a0.y, a0.z, a0.w, a1.x, a1.y, a1.z, a1.w};    \
      const float wv[8] = {w0.x, w0.y, w0.z, w0.w, w1.x, w1.y, w1.z, w1.w};    \
      _Pragma("unroll")                                                        \
      for (int j = 0; j < 8; ++j)                                              \
        _Pragma("unroll")                                                      \
        for (int i = 0; i < 8; ++i)                                            \
          acc[j][i] = fmaf(av[j], wv[i], acc[j][i]);                           \
    }                                                                          \
  }

  // 4 quarters x 3 phases of K=16. W quarter (48x64 = 12KB) staged at the
  // quarter head, piggybacking on phase 0's barrier pair. All global loads
  // issued BEFORE the barrier so they fly during the previous compute.
#pragma unroll 1
  for (int q = 0; q < 4; ++q) {
    const float* wsrc = We + (size_t)q * (48 * 64);
    f32v4 wq0 = *(const f32v4*)(wsrc + (0 * 256 + tid) * 4);
    f32v4 wq1 = *(const f32v4*)(wsrc + (1 * 256 + tid) * 4);
    f32v4 wq2 = *(const f32v4*)(wsrc + (2 * 256 + tid) * 4);
    f32v4 v0, v1, v2, v3;
    LOAD_A(q * 3);
    __syncthreads();  // prev quarter's compute done reading aT + Wb
    *(f32v4*)(&Wb[(0 * 256 + tid) * 4]) = wq0;
    *(f32v4*)(&Wb[(1 * 256 + tid) * 4]) = wq1;
    *(f32v4*)(&Wb[(2 * 256 + tid) * 4]) = wq2;
    WRITE_AT();
    __syncthreads();
    COMPUTE_PHASE(0);
#pragma unroll 1
    for (int p3 = 1; p3 < 3; ++p3) {
      LOAD_A(q * 3 + p3);
      __syncthreads();  // prev compute done reading aT
      WRITE_AT();
      __syncthreads();
      COMPUTE_PHASE(p3);
    }
  }
#undef LOAD_A
#undef WRITE_AT
#undef COMPUTE_PHASE
  __syncthreads();  // all waves done reading aT: safe to reuse as slices

  // ---- epilogue part 1: bias -> LN -> store; acc := n (pre-residual) ----
  const f32v4 be0 = *(const f32v4*)(be + tc);
  const f32v4 be1 = *(const f32v4*)(be + tc + 4);
  const f32v4 se0 = *(const f32v4*)(ln_s + tc);
  const f32v4 se1 = *(const f32v4*)(ln_s + tc + 4);
  const f32v4 bi0 = *(const f32v4*)(ln_b + tc);
  const f32v4 bi1 = *(const f32v4*)(ln_b + tc + 4);
  const float bb[8] = {be0.x, be0.y, be0.z, be0.w, be1.x, be1.y, be1.z, be1.w};
  const float ss[8] = {se0.x, se0.y, se0.z, se0.w, se1.x, se1.y, se1.z, se1.w};
  const float ll[8] = {bi0.x, bi0.y, bi0.z, bi0.w, bi1.x, bi1.y, bi1.z, bi1.w};

#pragma unroll
  for (int j = 0; j < 8; ++j) {
    const int row = te + j;
    const int ge = e0 + row;
    const bool valid = ge < NE;
    const int geC = valid ? ge : NE - 1;
    // residual re-read: cacheable (L2/L3-hot from the GEMM phase reads)
    const f32v4 r0 = *(const f32v4*)(edges + (size_t)geC * H + tc);
    const f32v4 r1 = *(const f32v4*)(edges + (size_t)geC * H + tc + 4);
    const float rr[8] = {r0.x, r0.y, r0.z, r0.w, r1.x, r1.y, r1.z, r1.w};
    float t8[8];
#pragma unroll
    for (int i = 0; i < 8; ++i) {
      const float n = acc[j][i] + bb[i];
      acc[j][i] = n;  // keep pre-residual value for the atomic pass
      t8[i] = n + rr[i];
    }
    float s1 = 0.f, s2 = 0.f;
#pragma unroll
    for (int i = 0; i < 8; ++i) { s1 += t8[i]; s2 = fmaf(t8[i], t8[i], s2); }
    // row held by the 8 lanes sharing te: xor 1,2,4
    s1 += __shfl_xor(s1, 1, 64); s2 += __shfl_xor(s2, 1, 64);
    s1 += __shfl_xor(s1, 2, 64); s2 += __shfl_xor(s2, 2, 64);
    s1 += __shfl_xor(s1, 4, 64); s2 += __shfl_xor(s2, 4, 64);
    const float mean = s1 * (1.0f / 64.0f);
    const float var = s2 * (1.0f / 64.0f) - mean * mean;
    const float rstd = rsqrtf(var + EPS);
    if (valid) {
      f32v4 o0, o1;
      o0.x = (t8[0] - mean) * rstd * ss[0] + ll[0];
      o0.y = (t8[1] - mean) * rstd * ss[1] + ll[1];
      o0.z = (t8[2] - mean) * rstd * ss[2] + ll[2];
      o0.w = (t8[3] - mean) * rstd * ss[3] + ll[3];
      o1.x = (t8[4] - mean) * rstd * ss[4] + ll[4];
      o1.y = (t8[5] - mean) * rstd * ss[5] + ll[5];
      o1.z = (t8[6] - mean) * rstd * ss[6] + ll[6];
      o1.w = (t8[7] - mean) * rstd * ss[7] + ll[7];
      float* po = edges_out + (size_t)ge * H + tc;
      __builtin_nontemporal_store(o0, (f32v4*)(po + 0));  // never re-read
      __builtin_nontemporal_store(o1, (f32v4*)(po + 4));
    }
  }

  // ---- epilogue part 2: per-wave transpose -> row-contiguous atomics ----
  // Wave wv owns block rows [64wv,64wv+64) + a private 4KB slice of aT: no
  // cross-wave hazard, no barriers. One atomic instr per edge covers the
  // full 256B recv row (8 sectors, 1x amplification) -- the r12 win.
  const int wv = tid >> 6;
  const int l = tid & 63;
  float* slice = aT + wv * 1024;  // 16 rows x 64 cols
#pragma unroll 1
  for (int s = 0; s < 4; ++s) {
    if ((l >> 4) == s) {
      const int rb = ((l >> 3) & 1) * 8;  // slice-row base for this lane
#pragma unroll
      for (int j = 0; j < 8; ++j) {
        f32v4 x0, x1;
        x0.x = acc[j][0]; x0.y = acc[j][1]; x0.z = acc[j][2]; x0.w = acc[j][3];
        x1.x = acc[j][4]; x1.y = acc[j][5]; x1.z = acc[j][6]; x1.w = acc[j][7];
        *(f32v4*)(&slice[(rb + j) * 64 + tc + 0]) = x0;
        *(f32v4*)(&slice[(rb + j) * 64 + tc + 4]) = x1;
      }
    }
#pragma unroll 4
    for (int e = 0; e < 16; ++e) {
      const int row = wv * 64 + s * 16 + e;
      const int ge = e0 + row;
      if (ge < NE) {  // uniform per instruction
        const float v = slice[e * 64 + l];  // stride-1 across lanes: free
        atomicAdd(recv_agg + (size_t)rBlk[row] * H + l, v);
      }
    }
  }
}

// ---- node kernel: unchanged (not the bottleneck, ~36 µs).
__global__ __launch_bounds__(256, 3) void node_tiled(
    const float* __restrict__ nodes, const float* recv_agg,
    const float* __restrict__ Wn, const float* __restrict__ bn,
    const float* __restrict__ ln_s, const float* __restrict__ ln_b,
    float* nodes_out) {
  __shared__ __align__(16) float aT[64 * 64];    // 16 KB: [k-k0][n]
  __shared__ __align__(16) float Wb[128 * 64];   // 32 KB
  const int tid = threadIdx.x;
  const int n0 = blockIdx.x * 64;

#pragma unroll
  for (int t = 0; t < 8; ++t) {
    int ci = t * 256 + tid;
    *(float4*)(&Wb[ci * 4]) = *(const float4*)(Wn + ci * 4);
  }

  float acc[4][4];
#pragma unroll
  for (int j = 0; j < 4; ++j)
#pragma unroll
    for (int i = 0; i < 4; ++i) acc[j][i] = 0.0f;

  const int te = (tid >> 4) * 4;
  const int tc = (tid & 15) * 4;

#pragma unroll
  for (int p = 0; p < 2; ++p) {
    const int k0 = 64 * p;
#pragma unroll
    for (int t = 0; t < 4; ++t) {
      int ci = t * 256 + tid;                     // 1024 float4
      int n = ci & 63, kq = ci >> 6;              // kq 0..15
      int kg = k0 + kq * 4;
      int gn = n0 + n;
      int gnc = gn < NN ? gn : NN - 1;
      const float* src = (kg < 64) ? (nodes + (size_t)gnc * H + kg)
                                   : (recv_agg + (size_t)gnc * H + (kg - 64));
      float4 v = *(const float4*)src;
      aT[(kq * 4 + 0) * 64 + n] = v.x;
      aT[(kq * 4 + 1) * 64 + n] = v.y;
      aT[(kq * 4 + 2) * 64 + n] = v.z;
      aT[(kq * 4 + 3) * 64 + n] = v.w;
    }
    __syncthreads();
#pragma unroll 4
    for (int kk = 0; kk < 64; ++kk) {
      float4 a4 = *(const float4*)(&aT[kk * 64 + te]);
      float4 w4 = *(const float4*)(&Wb[(k0 + kk) * 64 + tc]);
      float av[4] = {a4.x, a4.y, a4.z, a4.w};
      float wv[4] = {w4.x, w4.y, w4.z, w4.w};
#pragma unroll
      for (int j = 0; j < 4; ++j)
#pragma unroll
        for (int i = 0; i < 4; ++i) acc[j][i] += av[j] * wv[i];
    }
    __syncthreads();
  }

  const float4 bev = *(const float4*)(bn + tc);
  const float4 sev = *(const float4*)(ln_s + tc);
  const float4 biv = *(const float4*)(ln_b + tc);
#pragma unroll
  for (int j = 0; j < 4; ++j) {
    int gn = n0 + te + j;
    bool valid = gn < NN;
    float4 nv;
    if (valid) nv = *(const float4*)(nodes + (size_t)gn * H + tc);
    else { nv.x = nv.y = nv.z = nv.w = 0.0f; }
    float t0 = acc[j][0] + bev.x + nv.x;
    float t1 = acc[j][1] + bev.y + nv.y;
    float t2 = acc[j][2] + bev.z + nv.z;
    float t3 = acc[j][3] + bev.w + nv.w;
    float s1 = t0 + t1 + t2 + t3;
    float s2 = t0 * t0 + t1 * t1 + t2 * t2 + t3 * t3;
    s1 += __shfl_xor(s1, 1, 64); s2 += __shfl_xor(s2, 1, 64);
    s1 += __shfl_xor(s1, 2, 64); s2 += __shfl_xor(s2, 2, 64);
    s1 += __shfl_xor(s1, 4, 64); s2 += __shfl_xor(s2, 4, 64);
    s1 += __shfl_xor(s1, 8, 64); s2 += __shfl_xor(s2, 8, 64);
    float mean = s1 * (1.0f / 64.0f);
    float var = s2 * (1.0f / 64.0f) - mean * mean;
    float rstd = rsqrtf(var + EPS);
    if (valid) {
      float4 o;
      o.x = (t0 - mean) * rstd * sev.x + biv.x;
      o.y = (t1 - mean) * rstd * sev.y + biv.y;
      o.z = (t2 - mean) * rstd * sev.z + biv.z;
      o.w = (t3 - mean) * rstd * sev.w + biv.w;
      *(float4*)(nodes_out + (size_t)gn * H + tc) = o;
    }
  }
}

extern "C" void kernel_launch(void* const* d_in, const int* in_sizes, int n_in,
                              void* d_out, int out_size, void* d_ws, size_t ws_size,
                              hipStream_t stream) {
  const float* nodes      = (const float*)d_in[0];
  const float* edges      = (const float*)d_in[1];
  const int*   senders    = (const int*)d_in[2];
  const int*   receivers  = (const int*)d_in[3];
  const float* We         = (const float*)d_in[4];
  const float* be         = (const float*)d_in[5];
  const float* Wn         = (const float*)d_in[6];
  const float* bn         = (const float*)d_in[7];
  const float* ln_n_scale = (const float*)d_in[8];
  const float* ln_n_bias  = (const float*)d_in[9];
  const float* ln_e_scale = (const float*)d_in[10];
  const float* ln_e_bias  = (const float*)d_in[11];

  float* out = (float*)d_out;
  float* nodes_out = out;                       // [NN,64]; doubles as recv_agg
  float* edges_out = out + (size_t)NN * H;      // [NE,64]

  (void)hipMemsetAsync(nodes_out, 0, (size_t)NN * H * sizeof(float), stream);
  edge_q<<<(NE + 255) / 256, 256, 0, stream>>>(
      nodes, edges, senders, receivers, We, be, ln_e_scale, ln_e_bias,
      nodes_out, edges_out);
  node_tiled<<<(NN + 63) / 64, 256, 0, stream>>>(nodes, nodes_out, Wn, bn,
                                                 ln_n_scale, ln_n_bias, nodes_out);
}